// Round 7
// baseline (27.279 us; speedup 1.0000x reference)
//
#include <hip/hip_runtime.h>
#include <stdint.h>

typedef unsigned int u32;

#define FW   1024
#define NOUT 50
#define WPB  4      // waves per block
#define RPW  2      // rows per wave (r15: ILP restructure)
#define CAP  320    // compacted-candidate capacity (n~203, +9 sigma safe)
#define SPL  5      // max slots per lane (CAP/64); hot path uses 4 (n<=256)

// ---- DPP helpers (ctrl must be immediate) ----
// r10 POST-MORTEM: hand-fused v_max_u32_dpp + s_nop guards was NULL -- the
// s_nops ate exactly what the fusion saved. Keep the builtin form.
// r11/r12 POST-MORTEM: s_sleep desync at KERNEL ENTRY was +1.2us -- but the
// test was INVALID: the BW-bound memory phase re-syncs all waves at its
// drain, so the loop phase was never desynced. Do not re-run entry sleeps.
// r13 POST-MORTEM: readlane x4 + s_max tree REGRESSED (+1.3us): 4 serial
// VALU->SALU hazard crossings beat the 2 bcast DPP pairs they replaced.
// r14 POST-MORTEM: -4 ops/iter -> only -0.2us. Loop is CHAIN-LATENCY bound,
// not issue bound; clean op removal ~0.05us/op. Hence r15: in-wave ILP
// (2 independent rows per wave) to statically fill the chain bubbles.
#define DPP_UMAX_STEP(m, ctrl)                                                 \
  do {                                                                         \
    const u32 _t = (u32)__builtin_amdgcn_update_dpp(0, (int)(m), (ctrl),       \
                                                    0xf, 0xf, false);          \
    (m) = (m) > _t ? (m) : _t;                                                 \
  } while (0)
#define DPP_FMAX_STEP(m, ctrl)                                                 \
  do {                                                                         \
    const float _t = __uint_as_float((u32)__builtin_amdgcn_update_dpp(         \
        __float_as_int(m), __float_as_int(m), (ctrl), 0xf, 0xf, false));       \
    (m) = fmaxf((m), _t);                                                      \
  } while (0)
#define DPP_FMIN_STEP(m, ctrl)                                                 \
  do {                                                                         \
    const float _t = __uint_as_float((u32)__builtin_amdgcn_update_dpp(         \
        __float_as_int(m), __float_as_int(m), (ctrl), 0xf, 0xf, false));       \
    (m) = fminf((m), _t);                                                      \
  } while (0)
// inclusive add-scan step; row-masked bcast steps (round-7 lesson: 0xa/0xc)
#define DPP_SCAN_STEP(x, ctrl, rmask)                                          \
  do {                                                                         \
    const int _t = __builtin_amdgcn_update_dpp(0, (x), (ctrl), (rmask), 0xf,   \
                                               false);                         \
    (x) += _t;                                                                 \
  } while (0)

#define DPP_ALL6(OP, a)                                                        \
  OP(a, 0x111); OP(a, 0x112); OP(a, 0x114); OP(a, 0x118); OP(a, 0x142);        \
  OP(a, 0x143)

__device__ __forceinline__ u32 umax2(u32 a, u32 b) { return a > b ? a : b; }
__device__ __forceinline__ u32 umax3(u32 a, u32 b, u32 c) {
  return umax2(umax2(a, b), c);   // -> v_max3_u32
}

// r14 (kept): round-robin slot layout (slot k holds q = k*64+lane) so slot 4
// is empty whenever n <= 256 (true for essentially every row; n ~ 203+-13).
// Wave-uniform dispatch on the ACTUAL nc keeps the NS=5 path bit-exact.
// r15: both rows fused in one loop -- every serial link (tournament, DPP
// chain, readlane, uniform ds_read, suppress) has an independent twin the
// compiler interleaves. Two ds_reads share one lgkmcnt wait. Runtime `it`
// loop (unroll 2) keeps the fused body I$-resident (full unroll would be
// ~28KB). acckey update with runtime it: v_cmp + cndmask, same cost.
template <int NS>
__device__ __forceinline__ void run_nms2(
    const float2* __restrict__ kcA, const float2* __restrict__ kcB,
    int ncA, int ncB, int lane, float dtA, float dtB,
    u32& accA_o, u32& accB_o)
{
  u32 keysA[NS], keysB[NS];
  float centsA[NS], centsB[NS];
  {
    float2 slA[NS], slB[NS];
#pragma unroll
    for (int k = 0; k < NS; ++k) {          // batch issue all ds_reads
      slA[k] = kcA[k * 64 + lane];
      slB[k] = kcB[k * 64 + lane];
    }
#pragma unroll
    for (int k = 0; k < NS; ++k) {
      const int q2 = k * 64 + lane;
      keysA[k]  = (q2 < ncA) ? __float_as_uint(slA[k].x) : 0u;
      keysB[k]  = (q2 < ncB) ? __float_as_uint(slB[k].x) : 0u;
      centsA[k] = slA[k].y;                 // garbage for q2>=nc harmless
      centsB[k] = slB[k].y;
    }
  }

  u32 accA = 0, accB = 0;
#pragma unroll 2
  for (int it = 0; it < NOUT; ++it) {
    u32 mA = umax3(keysA[0], keysA[1], keysA[2]);
    u32 mB = umax3(keysB[0], keysB[1], keysB[2]);
#pragma unroll
    for (int k = 3; k < NS; ++k) { mA = umax2(mA, keysA[k]); mB = umax2(mB, keysB[k]); }
    // interleaved DPP chains: A's hazard slots filled by B's ops
    DPP_UMAX_STEP(mA, 0x111); DPP_UMAX_STEP(mB, 0x111);
    DPP_UMAX_STEP(mA, 0x112); DPP_UMAX_STEP(mB, 0x112);
    DPP_UMAX_STEP(mA, 0x114); DPP_UMAX_STEP(mB, 0x114);
    DPP_UMAX_STEP(mA, 0x118); DPP_UMAX_STEP(mB, 0x118);
    DPP_UMAX_STEP(mA, 0x142); DPP_UMAX_STEP(mB, 0x142);
    DPP_UMAX_STEP(mA, 0x143); DPP_UMAX_STEP(mB, 0x143);
    const u32 bestA = (u32)__builtin_amdgcn_readlane((int)mA, 63);
    const u32 bestB = (u32)__builtin_amdgcn_readlane((int)mB, 63);

    // winner slots (scalar); clamp handles best==0 (all keys 0 -> harmless)
    const int qsA  = 511 - (int)(bestA & 511u);
    const int qsB  = 511 - (int)(bestB & 511u);
    const int qscA = qsA < CAP ? qsA : CAP - 1;
    const int qscB = qsB < CAP ? qsB : CAP - 1;
    const float selA = kcA[qscA].y;   // two uniform ds_reads,
    const float selB = kcB[qscB].y;   // one lgkmcnt wait covers both
    // r9 POST-MORTEM (do not redo): register-resident sel_c via tournament+
    // ballot REGRESSED +3.4us; the 1-op uniform ds_read is the cheap form.

    accA = (lane == it) ? bestA : accA;
    accB = (lane == it) ? bestB : accB;

    // suppress |cent - sel| <= dthresh (includes self -> progress)
#pragma unroll
    for (int k = 0; k < NS; ++k) {
      keysA[k] = (fabsf(centsA[k] - selA) <= dtA) ? 0u : keysA[k];
      keysB[k] = (fabsf(centsB[k] - selB) <= dtB) ? 0u : keysB[k];
    }
  }
  accA_o = accA;
  accB_o = accB;
}

__global__ __launch_bounds__(256, 2) void nms1d_kernel(
    const float* __restrict__ logits,
    const float* __restrict__ delta,
    const int* __restrict__ iw_p,
    float* __restrict__ out_pos,   // [B,50,2]
    float* __restrict__ out_sc)    // [B,50]
{
  const int wave = threadIdx.x >> 6;
  const int lane = threadIdx.x & 63;
  const int b0 = (blockIdx.x * WPB + wave) * RPW;   // rows b0, b0+1

  // per-wave, per-row SoA slots + 1 dump slot (branchless scatter target).
  __shared__ float2 s_kc[WPB][RPW][CAP + 1];
  __shared__ float2 s_pp[WPB][RPW][CAP + 1];

  const float hi = (float)(*iw_p) - 1.0f;   // img_width - 1

  // ---- batch-issue ALL global loads for BOTH rows upfront ----
  float4 xl[RPW][4], dXa[RPW][4], dXb[RPW][4];
#pragma unroll
  for (int r = 0; r < RPW; ++r) {
    const float* __restrict__ lrow = logits + (size_t)(b0 + r) * FW;
#pragma unroll
    for (int c = 0; c < 4; ++c)
      xl[r][c] = *(const float4*)(lrow + lane * 16 + 4 * c);
  }
#pragma unroll
  for (int r = 0; r < RPW; ++r) {
    const float* __restrict__ drow = delta + (size_t)(b0 + r) * FW * 2;
#pragma unroll
    for (int c = 0; c < 4; ++c) {
      dXa[r][c] = *(const float4*)(drow + lane * 32 + 8 * c);
      dXb[r][c] = *(const float4*)(drow + lane * 32 + 8 * c + 4);
    }
  }

  // ---- pass 1: sigmoid + per-lane valid count + prefix scan, per row ----
  float sc[RPW][16];
  int incl[RPW], base_[RPW];
#pragma unroll
  for (int r = 0; r < RPW; ++r) {
    int v = 0;
#pragma unroll
    for (int c = 0; c < 4; ++c) {
      const float xs[4] = {xl[r][c].x, xl[r][c].y, xl[r][c].z, xl[r][c].w};
#pragma unroll
      for (int j = 0; j < 4; ++j) {
        const float s = 1.0f / (1.0f + expf(-xs[j]));  // frozen: bit-matched
        sc[r][c * 4 + j] = s;
        v += (s >= 0.7f) ? 1 : 0;
      }
    }
    int ic = v;       // canonical masked scan, proven r8
    DPP_SCAN_STEP(ic, 0x111, 0xf);   // row_shr:1
    DPP_SCAN_STEP(ic, 0x112, 0xf);   // row_shr:2
    DPP_SCAN_STEP(ic, 0x114, 0xf);   // row_shr:4
    DPP_SCAN_STEP(ic, 0x118, 0xf);   // row_shr:8
    DPP_SCAN_STEP(ic, 0x142, 0xa);   // row_bcast:15 -> rows 1,3 only
    DPP_SCAN_STEP(ic, 0x143, 0xc);   // row_bcast:31 -> rows 2,3 only
    incl[r]  = ic;
    base_[r] = ic - v;
  }

  // ---- pass 2: positions/centers, branchless compacted scatter, dthresh ----
  float dthr[RPW];
  int nfin[RPW];
#pragma unroll
  for (int r = 0; r < RPW; ++r) {
    float2* __restrict__ kc = s_kc[wave][r];
    float2* __restrict__ pp = s_pp[wave][r];
    float vmin = INFINITY, vmax = -INFINITY;
    int q = base_[r];
#pragma unroll
    for (int c = 0; c < 4; ++c) {
      const float dx[4] = {dXa[r][c].x, dXa[r][c].z, dXb[r][c].x, dXb[r][c].z};
      const float dy[4] = {dXa[r][c].y, dXa[r][c].w, dXb[r][c].y, dXb[r][c].w};
#pragma unroll
      for (int j = 0; j < 4; ++j) {
        const int e = c * 4 + j;
        const int f = lane * 16 + e;
        const float center = (float)f * 16.0f + 8.0f;   // (f+0.5)*16, exact
        float p0 = dx[j] * 16.0f + center;   // frozen: bit-matched ref
        float p1 = dy[j] * 16.0f + center;
        p0 = fminf(fmaxf(p0, 0.0f), hi);
        p1 = fminf(fmaxf(p1, 0.0f), hi);
        const float cc = (p0 + p1) * 0.5f;
        const float s = sc[r][e];
        const bool valid = (s >= 0.7f);
        vmin = valid ? fminf(vmin, cc) : vmin;   // cndmask, no exec write
        vmax = valid ? fmaxf(vmax, cc) : vmax;
        // branchless scatter: invalid (or overflow) elements hit dump slot
        const int qd = (valid && q < CAP) ? q : CAP;
        // u32 key: s in [0.7,1] -> bits-diff fits 23 bits; <<9 | (511-q)
        // exact order w/ first-index tie-break (lower q = lower f).
        const u32 key = ((__float_as_uint(s) - 0x3F333333u) << 9) | (u32)(511 - q);
        kc[qd] = make_float2(__uint_as_float(key), cc);
        pp[qd] = make_float2(p0, p1);
        q += valid ? 1 : 0;
      }
    }
    // wave min/max via DPP (old=self identity; exact). Lane 63 holds result.
    DPP_ALL6(DPP_FMIN_STEP, vmin);
    DPP_ALL6(DPP_FMAX_STEP, vmax);
    const float dt_part = (0.55f * (vmax - vmin)) / ((float)incl[r] - 1.0f);
    dthr[r] = __uint_as_float(
        (u32)__builtin_amdgcn_readlane(__float_as_int(dt_part), 63));
    // n==1 -> NaN -> suppresses nothing (ref match); n>=2 -> self-suppress
    nfin[r] = __builtin_amdgcn_readlane(incl[r], 63);
  }

  // ---- greedy NMS: both rows fused, wave-uniform slot-count dispatch ----
  const int ncA = nfin[0] < CAP ? nfin[0] : CAP;
  const int ncB = nfin[1] < CAP ? nfin[1] : CAP;
  u32 accA, accB;
  if (ncA <= 256 && ncB <= 256)
    run_nms2<4>(s_kc[wave][0], s_kc[wave][1], ncA, ncB, lane,
                dthr[0], dthr[1], accA, accB);     // hot: ~always
  else
    run_nms2<5>(s_kc[wave][0], s_kc[wave][1], ncA, ncB, lane,
                dthr[0], dthr[1], accA, accB);     // cold, bit-exact

  // ---- epilogue: decode acckeys, fetch p0/p1, coalesced writes ----
  if (lane < NOUT) {
#pragma unroll
    for (int r = 0; r < RPW; ++r) {
      const u32 ak = (r == 0) ? accA : accB;
      const float2* __restrict__ pp = s_pp[wave][r];
      float p0 = 0.0f, p1 = 0.0f, s = 0.0f;
      if (ak != 0u) {
        const int qw = 511 - (int)(ak & 511u);    // valid -> qw < CAP
        const float2 sl = pp[qw];
        p0 = sl.x;
        p1 = sl.y;
        s  = __uint_as_float((ak >> 9) + 0x3F333333u);   // exact score bits
      }
      float* __restrict__ orow_p = out_pos + (size_t)(b0 + r) * NOUT * 2;
      float* __restrict__ orow_s = out_sc  + (size_t)(b0 + r) * NOUT;
      *(float2*)(orow_p + lane * 2) = make_float2(p0, p1);
      orow_s[lane] = s;
    }
  }
}

extern "C" void kernel_launch(void* const* d_in, const int* in_sizes, int n_in,
                              void* d_out, int out_size, void* d_ws, size_t ws_size,
                              hipStream_t stream) {
  const float* logits = (const float*)d_in[0];
  const float* delta  = (const float*)d_in[1];
  const int*   iw     = (const int*)d_in[2];
  const int B = in_sizes[0] / FW;            // 4096
  float* out_pos = (float*)d_out;                         // B*50*2
  float* out_sc  = (float*)d_out + (size_t)B * NOUT * 2;  // B*50
  const int rows_per_block = WPB * RPW;      // 8
  nms1d_kernel<<<(B + rows_per_block - 1) / rows_per_block, WPB * 64, 0, stream>>>(
      logits, delta, iw, out_pos, out_sc);
}

// Round 8
// 25.736 us; speedup vs baseline: 1.0600x; 1.0600x over previous
//
#include <hip/hip_runtime.h>
#include <stdint.h>

typedef unsigned int u32;

#define FW   1024
#define NOUT 50
#define RPB  4      // rows (waves) per 256-thread block
#define CAP  320    // compacted-candidate capacity (n~203, +9 sigma safe)
#define SPL  5      // max slots per lane (CAP/64); hot path uses 4 (n<=256)

// ---- DPP helpers (ctrl must be immediate) ----
// r10 POST-MORTEM: hand-fused v_max_u32_dpp + s_nop guards was NULL -- the
// s_nops ate exactly what the fusion saved. Keep the builtin form.
// r13 POST-MORTEM: readlane x4 + s_max tree REGRESSED (+1.3us): 4 serial
// VALU->SALU hazard crossings beat the 2 bcast DPP pairs they replaced.
// r14 POST-MORTEM: -4 ops/iter -> only -0.2us (best, 25.69). Loop is
// CHAIN-latency bound; clean op removal ~0.05us/op.
// r15 POST-MORTEM: 2-rows-per-wave ILP REGRESSED (+1.6us): halved TLP +
// runtime-loop overhead + VGPR pressure outweighed static interleave.
// 4 waves/SIMD with full unroll is the right shape. REVERTED to r14.
#define DPP_UMAX_STEP(m, ctrl)                                                 \
  do {                                                                         \
    const u32 _t = (u32)__builtin_amdgcn_update_dpp(0, (int)(m), (ctrl),       \
                                                    0xf, 0xf, false);          \
    (m) = (m) > _t ? (m) : _t;                                                 \
  } while (0)
#define DPP_FMAX_STEP(m, ctrl)                                                 \
  do {                                                                         \
    const float _t = __uint_as_float((u32)__builtin_amdgcn_update_dpp(         \
        __float_as_int(m), __float_as_int(m), (ctrl), 0xf, 0xf, false));       \
    (m) = fmaxf((m), _t);                                                      \
  } while (0)
#define DPP_FMIN_STEP(m, ctrl)                                                 \
  do {                                                                         \
    const float _t = __uint_as_float((u32)__builtin_amdgcn_update_dpp(         \
        __float_as_int(m), __float_as_int(m), (ctrl), 0xf, 0xf, false));       \
    (m) = fminf((m), _t);                                                      \
  } while (0)
// inclusive add-scan step; row-masked bcast steps (round-7 lesson: 0xa/0xc)
#define DPP_SCAN_STEP(x, ctrl, rmask)                                          \
  do {                                                                         \
    const int _t = __builtin_amdgcn_update_dpp(0, (x), (ctrl), (rmask), 0xf,   \
                                               false);                         \
    (x) += _t;                                                                 \
  } while (0)

#define DPP_ALL6(OP, a)                                                        \
  OP(a, 0x111); OP(a, 0x112); OP(a, 0x114); OP(a, 0x118); OP(a, 0x142);        \
  OP(a, 0x143)

__device__ __forceinline__ u32 umax2(u32 a, u32 b) { return a > b ? a : b; }
__device__ __forceinline__ u32 umax3(u32 a, u32 b, u32 c) {
  return umax2(umax2(a, b), c);   // -> v_max3_u32
}

// r14 (kept): round-robin slot layout (slot k holds q = k*64+lane) so slot 4
// is empty whenever n <= 256 (true for essentially every row; n ~ 203+-13).
// Wave-uniform dispatch on the ACTUAL nc keeps the NS=5 path bit-exact.
template <int NS>
__device__ __forceinline__ u32 run_nms(const float2* __restrict__ kc, int nc,
                                       int lane, float dthresh) {
  u32 keys[NS];
  float cents[NS];
  {
    float2 sl[NS];
#pragma unroll
    for (int k = 0; k < NS; ++k) sl[k] = kc[k * 64 + lane];   // batch issue
#pragma unroll
    for (int k = 0; k < NS; ++k) {
      const int q2 = k * 64 + lane;
      keys[k]  = (q2 < nc) ? __float_as_uint(sl[k].x) : 0u;
      cents[k] = sl[k].y;          // garbage for q2>=nc harmless (key==0)
    }
  }

  u32 acckey = 0;        // lane j: winner key of output j (0 = none)
#pragma unroll
  for (int it = 0; it < NOUT; ++it) {
    u32 m = umax3(keys[0], keys[1], keys[2]);
#pragma unroll
    for (int k = 3; k < NS; ++k) m = umax2(m, keys[k]);
    DPP_UMAX_STEP(m, 0x111);
    DPP_UMAX_STEP(m, 0x112);
    DPP_UMAX_STEP(m, 0x114);
    DPP_UMAX_STEP(m, 0x118);
    DPP_UMAX_STEP(m, 0x142);
    DPP_UMAX_STEP(m, 0x143);
    const u32 best = (u32)__builtin_amdgcn_readlane((int)m, 63);   // SGPR

    // winner slot (scalar); clamp handles best==0 (keys all 0 -> harmless)
    const int qs  = 511 - (int)(best & 511u);
    const int qsc = qs < CAP ? qs : CAP - 1;
    const float sel_c = kc[qsc].y;      // uniform-addr ds_read broadcast
    // r9 POST-MORTEM (do not redo): register-resident sel_c via tournament+
    // ballot REGRESSED +3.4us; the 1-op uniform ds_read is the cheap form.

    // lane `it` keeps the winner key (it is a LITERAL here: v_cmp + cndmask)
    acckey = (lane == it) ? best : acckey;

    // suppress |cent - sel_c| <= dthresh (includes self -> progress)
#pragma unroll
    for (int k = 0; k < NS; ++k) {
      keys[k] = (fabsf(cents[k] - sel_c) <= dthresh) ? 0u : keys[k];
    }
  }
  return acckey;
}

__global__ __launch_bounds__(256, 4) void nms1d_kernel(
    const float* __restrict__ logits,
    const float* __restrict__ delta,
    const int* __restrict__ iw_p,
    float* __restrict__ out_pos,   // [B,50,2]
    float* __restrict__ out_sc)    // [B,50]
{
  const int wave = threadIdx.x >> 6;
  const int lane = threadIdx.x & 63;
  const int b = blockIdx.x * RPB + wave;

  // per-wave SoA slots + 1 dump slot (branchless scatter target).
  __shared__ float2 s_kc[RPB][CAP + 1];
  __shared__ float2 s_pp[RPB][CAP + 1];
  float2* __restrict__ kc = s_kc[wave];
  float2* __restrict__ pp = s_pp[wave];

  const float hi = (float)(*iw_p) - 1.0f;   // img_width - 1

  const float* __restrict__ lrow = logits + (size_t)b * FW;
  const float* __restrict__ drow = delta  + (size_t)b * FW * 2;

  // ---- batch-issue ALL global loads upfront (one latency exposure).
  float4 xl0 = *(const float4*)(lrow + lane * 16 + 0);
  float4 xl1 = *(const float4*)(lrow + lane * 16 + 4);
  float4 xl2 = *(const float4*)(lrow + lane * 16 + 8);
  float4 xl3 = *(const float4*)(lrow + lane * 16 + 12);
  float4 dA0 = *(const float4*)(drow + lane * 32 + 0);
  float4 dB0 = *(const float4*)(drow + lane * 32 + 4);
  float4 dA1 = *(const float4*)(drow + lane * 32 + 8);
  float4 dB1 = *(const float4*)(drow + lane * 32 + 12);
  float4 dA2 = *(const float4*)(drow + lane * 32 + 16);
  float4 dB2 = *(const float4*)(drow + lane * 32 + 20);
  float4 dA3 = *(const float4*)(drow + lane * 32 + 24);
  float4 dB3 = *(const float4*)(drow + lane * 32 + 28);

  // ---- pass 1: sigmoid + per-lane valid count (lane owns f = lane*16+e) ----
  float sc[16];
  int v = 0;
  const float4 xls[4] = {xl0, xl1, xl2, xl3};
#pragma unroll
  for (int c = 0; c < 4; ++c) {
    const float xs[4] = {xls[c].x, xls[c].y, xls[c].z, xls[c].w};
#pragma unroll
    for (int j = 0; j < 4; ++j) {
      const float s = 1.0f / (1.0f + expf(-xs[j]));   // frozen: bit-matched ref
      sc[c * 4 + j] = s;
      v += (s >= 0.7f) ? 1 : 0;
    }
  }

  // inclusive prefix sum over lanes via DPP (canonical masked scan, proven r8)
  int incl = v;
  DPP_SCAN_STEP(incl, 0x111, 0xf);   // row_shr:1
  DPP_SCAN_STEP(incl, 0x112, 0xf);   // row_shr:2
  DPP_SCAN_STEP(incl, 0x114, 0xf);   // row_shr:4
  DPP_SCAN_STEP(incl, 0x118, 0xf);   // row_shr:8
  DPP_SCAN_STEP(incl, 0x142, 0xa);   // row_bcast:15 -> rows 1,3 only
  DPP_SCAN_STEP(incl, 0x143, 0xc);   // row_bcast:31 -> rows 2,3 only
  const int base = incl - v;
  const int n = __builtin_amdgcn_readlane(incl, 63);

  // ---- pass 2: positions/centers, BRANCHLESS compacted scatter, vmin/vmax --
  float vmin = INFINITY, vmax = -INFINITY;
  int q = base;
  const float4 dAs[4] = {dA0, dA1, dA2, dA3};
  const float4 dBs[4] = {dB0, dB1, dB2, dB3};
#pragma unroll
  for (int c = 0; c < 4; ++c) {
    const float dx[4] = {dAs[c].x, dAs[c].z, dBs[c].x, dBs[c].z};
    const float dy[4] = {dAs[c].y, dAs[c].w, dBs[c].y, dBs[c].w};
#pragma unroll
    for (int j = 0; j < 4; ++j) {
      const int e = c * 4 + j;
      const int f = lane * 16 + e;
      const float center = (float)f * 16.0f + 8.0f;   // (f+0.5)*16, exact
      float p0 = dx[j] * 16.0f + center;              // frozen: bit-matched ref
      float p1 = dy[j] * 16.0f + center;
      p0 = fminf(fmaxf(p0, 0.0f), hi);
      p1 = fminf(fmaxf(p1, 0.0f), hi);
      const float cc = (p0 + p1) * 0.5f;
      const float s = sc[e];
      const bool valid = (s >= 0.7f);
      vmin = valid ? fminf(vmin, cc) : vmin;          // cndmask, no exec write
      vmax = valid ? fmaxf(vmax, cc) : vmax;
      // branchless scatter: invalid (or overflow) elements hit dump slot CAP
      const int qd = (valid && q < CAP) ? q : CAP;
      // u32 key: s in [0.7,1] -> bits-diff fits 23 bits; <<9 | (511-q)
      // exact order w/ first-index tie-break (lower q = lower f).
      const u32 key = ((__float_as_uint(s) - 0x3F333333u) << 9) | (u32)(511 - q);
      kc[qd] = make_float2(__uint_as_float(key), cc);
      pp[qd] = make_float2(p0, p1);
      q += valid ? 1 : 0;
    }
  }

  // wave min/max via DPP (old=self identity; exact). Lane 63 holds the result.
  DPP_ALL6(DPP_FMIN_STEP, vmin);
  DPP_ALL6(DPP_FMAX_STEP, vmax);
  const float dt_part = (0.55f * (vmax - vmin)) / ((float)incl - 1.0f);
  const float dthresh = __uint_as_float(
      (u32)__builtin_amdgcn_readlane(__float_as_int(dt_part), 63));
  // n==1 -> NaN -> suppresses nothing (matches ref); n>=2 -> >=0 -> self-suppress

  // r16: POST-SCATTER, PER-BLOCK phase desync. r11's entry/per-wave sleeps
  // tested NOTHING: (a) the BW-bound memory phase re-syncs at its drain, so
  // an entry stagger dies before the loop; (b) a block's 4 waves sit on
  // DIFFERENT SIMDs -- the waves sharing a SIMD are wave-w of the 4
  // co-resident BLOCKS, so the stagger key must be per-block. Offsets
  // 0/128/256/384 cy (> half the ~230cy per-iter chain) break the lockstep
  // where all 4 co-SIMD waves hit the ~120cy uniform ds_read wait in the
  // same window. Key covers both consecutive and stride-256 co-residency.
  // Tail cost <= 0.16us. Loop durations are identical -> offsets persist.
  {
    const u32 phase = ((u32)(blockIdx.x & 3) + (u32)((blockIdx.x >> 8) & 3)) & 3u;
    if (phase == 1u)      __builtin_amdgcn_s_sleep(2);   // ~128 cy
    else if (phase == 2u) __builtin_amdgcn_s_sleep(4);   // ~256 cy
    else if (phase == 3u) __builtin_amdgcn_s_sleep(6);   // ~384 cy
  }

  // ---- greedy NMS: 50 iters, branchless, FULLY UNROLLED ----
  // wave-uniform dispatch on slot count (see run_nms comment).
  const int nc = n < CAP ? n : CAP;
  u32 acckey;
  if (nc <= 256) acckey = run_nms<4>(kc, nc, lane, dthresh);   // hot: ~always
  else           acckey = run_nms<5>(kc, nc, lane, dthresh);   // cold, exact

  // ---- epilogue: decode acckey, fetch p0/p1, single coalesced write ----
  if (lane < NOUT) {
    float p0 = 0.0f, p1 = 0.0f, s = 0.0f;
    if (acckey != 0u) {
      const int qw = 511 - (int)(acckey & 511u);    // valid -> qw < CAP
      const float2 sl = pp[qw];
      p0 = sl.x;
      p1 = sl.y;
      s  = __uint_as_float((acckey >> 9) + 0x3F333333u);   // exact score bits
    }
    float* __restrict__ orow_p = out_pos + (size_t)b * NOUT * 2;
    float* __restrict__ orow_s = out_sc  + (size_t)b * NOUT;
    *(float2*)(orow_p + lane * 2) = make_float2(p0, p1);
    orow_s[lane] = s;
  }
}

extern "C" void kernel_launch(void* const* d_in, const int* in_sizes, int n_in,
                              void* d_out, int out_size, void* d_ws, size_t ws_size,
                              hipStream_t stream) {
  const float* logits = (const float*)d_in[0];
  const float* delta  = (const float*)d_in[1];
  const int*   iw     = (const int*)d_in[2];
  const int B = in_sizes[0] / FW;            // 4096
  float* out_pos = (float*)d_out;                         // B*50*2
  float* out_sc  = (float*)d_out + (size_t)B * NOUT * 2;  // B*50
  nms1d_kernel<<<(B + RPB - 1) / RPB, RPB * 64, 0, stream>>>(logits, delta, iw, out_pos, out_sc);
}